// Round 1
// baseline (614.037 us; speedup 1.0000x reference)
//
#include <hip/hip_runtime.h>

#define LENF 15
#define PFD  15          // prefetch distance = one unrolled macro-block
#define NZ   1e-5f

__global__ __launch_bounds__(64) void exphydro_kernel(
    const float* __restrict__ x,      // (T, G, 3): prcp, tmean, pet
    const float* __restrict__ params, // (G, 16)
    float* __restrict__ out,          // (T, G)
    int G, int T)
{
  int g = blockIdx.x * 64 + threadIdx.x;
  if (g >= G) return;

  // ---- load & descale per-cell params (row is 64B-aligned) ----
  const float* pp = params + (size_t)g * 16;
  float P0[16];
  #pragma unroll
  for (int i = 0; i < 16; ++i) P0[i] = pp[i];

  const float ddf    = P0[0]  * 40.f;
  const float Tbm    = P0[1]  * 5.f  - 2.f;
  const float wrf    = P0[2]  * 0.5f;
  const float Tbf    = P0[3]  * 7.f  - 5.f;
  const float Kf     = P0[4]  * 5.f;
  const float exp_fe = P0[5];
  const float ET_eff = P0[6];
  const float c_run  = P0[7];
  const float c_v2p  = P0[8]  * (0.02f - 1e-5f) + 1e-5f;
  const float c_vad  = P0[9]  * 0.1f;
  const float c_phr  = P0[10] * (0.01f - 1e-5f) + 1e-5f;
  const float vml    = P0[11] * (500.f - 0.001f) + 0.001f;
  const float a1     = P0[12] * (20.f - 0.3f)  + 0.3f;
  const float b1     = P0[13] * (5.f  - 0.01f) + 0.01f;
  const float a2     = P0[14] * (13.f - 0.5f)  + 0.5f;
  const float b2     = P0[15] * (1.5f - 0.15f) + 0.15f;
  const float inv_vml = 1.f / vml;

  // ---- gamma unit-hydrograph weights ----
  // logw = (a-1)ln(t) - t/theta - gammaln(a) - a*ln(theta); the last two terms
  // are tap-independent and cancel under normalization -> no lgamma needed.
  float w1[LENF], w2[LENF];
  {
    float lw1[LENF], lw2[LENF];
    float m1 = -1e30f, m2 = -1e30f;
    const float ib1 = 1.f / b1, ib2 = 1.f / b2;
    #pragma unroll
    for (int l = 0; l < LENF; ++l) {
      float tt = l + 0.5f;
      float lt = __logf(tt);
      lw1[l] = (a1 - 1.f) * lt - tt * ib1;
      lw2[l] = (a2 - 1.f) * lt - tt * ib2;
      m1 = fmaxf(m1, lw1[l]);
      m2 = fmaxf(m2, lw2[l]);
    }
    float s1 = 0.f, s2 = 0.f;
    #pragma unroll
    for (int l = 0; l < LENF; ++l) {
      w1[l] = __expf(lw1[l] - m1); s1 += w1[l];
      w2[l] = __expf(lw2[l] - m2); s2 += w2[l];
    }
    const float r1 = 1.f / s1, r2 = 1.f / s2;
    #pragma unroll
    for (int l = 0; l < LENF; ++l) { w1[l] *= r1; w2[l] *= r2; }
  }

  // ---- state, conv ring (zeros = left zero-padding), prefetch pipeline ----
  float sog = NZ, wis = NZ, vad = NZ, phr = NZ;
  float qs[LENF], qd[LENF];
  #pragma unroll
  for (int l = 0; l < LENF; ++l) { qs[l] = 0.f; qd[l] = 0.f; }

  float bp[PFD], bt[PFD], bpe[PFD];
  #pragma unroll
  for (int i = 0; i < PFD; ++i) {
    if (i < T) {
      const float* s = x + ((size_t)i * G + g) * 3;
      bp[i] = s[0]; bt[i] = s[1]; bpe[i] = s[2];
    } else { bp[i] = 0.f; bt[i] = 0.f; bpe[i] = 0.f; }
  }

  // T = 1095 = 73 * 15, so ring slot == i (compile-time) inside the unroll.
  for (int tb = 0; tb < T; tb += LENF) {
    #pragma unroll
    for (int i = 0; i < LENF; ++i) {
      int t = tb + i;
      if (t < T) {
        float p = bp[i], tm = bt[i], pe = bpe[i];
        // prefetch t+15 into the slot we just consumed
        int tf = t + PFD;
        if (tf < T) {
          const float* s = x + ((size_t)tf * G + g) * 3;
          bp[i] = s[0]; bt[i] = s[1]; bpe[i] = s[2];
        }

        // ---- one scan step ----
        bool warm = (tm >= 0.f);
        float rain = warm ? p : 0.f;
        float snow = warm ? 0.f : p;
        float pot_freeze = Kf * __expf(exp_fe * __logf(fmaxf(Tbf - tm, NZ)));
        float freeze = fminf(pot_freeze, wis);
        wis -= freeze;
        sog += freeze;
        float melt = fminf(fmaxf(ddf * (tm - Tbm), 0.f), sog + snow);
        sog = sog + snow - melt;
        float retention = wrf * sog;
        float wtmp = wis + melt + rain;
        float avail = fmaxf(wtmp - retention, 0.f);
        wis = (avail > 0.f) ? retention : wtmp;
        float ret_pot = ET_eff * pe;
        float ratio = vad * inv_vml;
        float ht0 = c_run * ratio * avail;
        float infil = avail - ht0;
        float ht1 = c_v2p * ratio * vad;
        float ht2 = c_vad * vad;
        float ht3 = c_phr * phr;
        float aet = fminf(ret_pot, vad);
        vad = vad + infil - aet - ht1 - ht2;
        float overflow = fmaxf(vad - vml, 0.f);
        vad = fminf(fmaxf(vad, NZ), vml);
        ht0 += overflow;
        phr = fmaxf(phr + ht1 - ht3, NZ);

        qs[i] = ht0;          // slot i == t % 15
        qd[i] = ht2 + ht3;

        // ---- fused causal 15-tap conv: out[t] = sum_l w[l] * q[t-l] ----
        float o = 0.f;
        #pragma unroll
        for (int l = 0; l < LENF; ++l) {
          int idx = i - l; if (idx < 0) idx += LENF;   // compile-time
          o = fmaf(w1[l], qs[idx], o);
          o = fmaf(w2[l], qd[idx], o);
        }
        out[(size_t)t * G + g] = o;
      }
    }
  }
}

extern "C" void kernel_launch(void* const* d_in, const int* in_sizes, int n_in,
                              void* d_out, int out_size, void* d_ws, size_t ws_size,
                              hipStream_t stream) {
  const float* x      = (const float*)d_in[0];
  const float* params = (const float*)d_in[1];
  float* out          = (float*)d_out;

  int G = in_sizes[1] / 16;               // 15000
  int T = in_sizes[0] / (G * 3);          // 1095

  int block = 64;                         // 1 wave/block -> spread 235 waves over 235 CUs
  int grid  = (G + block - 1) / block;
  exphydro_kernel<<<grid, block, 0, stream>>>(x, params, out, G, T);
}

// Round 2
// 206.907 us; speedup vs baseline: 2.9677x; 2.9677x over previous
//
#include <hip/hip_runtime.h>

#define LENF 15
#define NZ   1e-5f

__global__ __launch_bounds__(64, 1) void exphydro_kernel(
    const float* __restrict__ x,      // (T, G, 3): prcp, tmean, pet
    const float* __restrict__ params, // (G, 16)
    float* __restrict__ out,          // (T, G)
    int G, int T)
{
  int g = blockIdx.x * 64 + threadIdx.x;
  if (g >= G) return;

  // ---- load & descale per-cell params ----
  const float* pp = params + (size_t)g * 16;
  float P0[16];
#pragma unroll
  for (int i = 0; i < 16; ++i) P0[i] = pp[i];

  const float ddf    = P0[0]  * 40.f;
  const float Tbm    = P0[1]  * 5.f  - 2.f;
  const float wrf    = P0[2]  * 0.5f;
  const float Tbf    = P0[3]  * 7.f  - 5.f;
  const float Kf     = P0[4]  * 5.f;
  const float exp_fe = P0[5];
  const float ET_eff = P0[6];
  const float c_run  = P0[7];
  const float c_v2p  = P0[8]  * (0.02f - 1e-5f) + 1e-5f;
  const float c_vad  = P0[9]  * 0.1f;
  const float c_phr  = P0[10] * (0.01f - 1e-5f) + 1e-5f;
  const float vml    = P0[11] * (500.f - 0.001f) + 0.001f;
  const float a1     = P0[12] * (20.f - 0.3f)  + 0.3f;
  const float b1     = P0[13] * (5.f  - 0.01f) + 0.01f;
  const float a2     = P0[14] * (13.f - 0.5f)  + 0.5f;
  const float b2     = P0[15] * (1.5f - 0.15f) + 0.15f;
  const float inv_vml = 1.f / vml;

  // ---- gamma UH weights (lgamma terms cancel under normalization) ----
  float w1[LENF], w2[LENF];
  {
    float lw1[LENF], lw2[LENF];
    float m1 = -1e30f, m2 = -1e30f;
    const float ib1 = 1.f / b1, ib2 = 1.f / b2;
#pragma unroll
    for (int l = 0; l < LENF; ++l) {
      float tt = l + 0.5f;
      float lt = __logf(tt);
      lw1[l] = (a1 - 1.f) * lt - tt * ib1;
      lw2[l] = (a2 - 1.f) * lt - tt * ib2;
      m1 = fmaxf(m1, lw1[l]);
      m2 = fmaxf(m2, lw2[l]);
    }
    float s1 = 0.f, s2 = 0.f;
#pragma unroll
    for (int l = 0; l < LENF; ++l) {
      w1[l] = __expf(lw1[l] - m1); s1 += w1[l];
      w2[l] = __expf(lw2[l] - m2); s2 += w2[l];
    }
    const float r1 = 1.f / s1, r2 = 1.f / s2;
#pragma unroll
    for (int l = 0; l < LENF; ++l) { w1[l] *= r1; w2[l] *= r2; }
  }

  // ---- state + scatter-conv accumulator ring ----
  float sog = NZ, wis = NZ, vad = NZ, phr = NZ;
  float acc[LENF];
#pragma unroll
  for (int l = 0; l < LENF; ++l) acc[l] = 0.f;

  const size_t strideT = (size_t)3 * G;   // floats per time step in x
  const float* xg = x + (size_t)g * 3;
  float* optr = out + g;

  float Ap[LENF], At[LENF], Ae[LENF];
  float Bp[LENF], Bt[LENF], Be[LENF];

  const int nb   = T / LENF;              // full 15-step blocks
  const int tail = T - nb * LENF;

  // Issue all 15 loads of a block up-front (double-buffered with compute).
#define LOAD_BLOCK(BP, BT, BE, blk)                                  \
  {                                                                  \
    const float* base_ = xg + (size_t)(blk) * LENF * strideT;        \
    _Pragma("unroll")                                                \
    for (int j = 0; j < LENF; ++j) {                                 \
      const float* s_ = base_ + (size_t)j * strideT;                 \
      BP[j] = s_[0]; BT[j] = s_[1]; BE[j] = s_[2];                   \
    }                                                                \
  }

#define LOAD_BLOCK_GUARDED(BP, BT, BE, blk)                          \
  {                                                                  \
    const float* base_ = xg + (size_t)(blk) * LENF * strideT;        \
    _Pragma("unroll")                                                \
    for (int j = 0; j < LENF; ++j) {                                 \
      if ((blk) * LENF + j < T) {                                    \
        const float* s_ = base_ + (size_t)j * strideT;               \
        BP[j] = s_[0]; BT[j] = s_[1]; BE[j] = s_[2];                 \
      } else { BP[j] = 0.f; BT[j] = 0.f; BE[j] = 0.f; }              \
    }                                                                \
  }

  // One scan step; I_ is a compile-time constant after unrolling, so all
  // acc[] indices are static (no scratch).
#define STEP(p_, tm_, pe_, I_)                                       \
  {                                                                  \
    float p = (p_), tm = (tm_), pe = (pe_);                          \
    bool warm = (tm >= 0.f);                                         \
    float rain = warm ? p : 0.f;                                     \
    float snow = warm ? 0.f : p;                                     \
    float pot_freeze = Kf * __expf(exp_fe * __logf(fmaxf(Tbf - tm, NZ))); \
    float freeze = fminf(pot_freeze, wis);                           \
    wis -= freeze;                                                   \
    sog += freeze;                                                   \
    float sos = sog + snow;                                          \
    float melt = fminf(fmaxf(ddf * (tm - Tbm), 0.f), sos);           \
    sog = sos - melt;                                                \
    float retention = wrf * sog;                                     \
    float wtmp = wis + melt + rain;                                  \
    float avail = fmaxf(wtmp - retention, 0.f);                      \
    wis = (avail > 0.f) ? retention : wtmp;                          \
    float ratio = vad * inv_vml;                                     \
    float ht0 = c_run * ratio * avail;                               \
    float infil = avail - ht0;                                       \
    float ht1 = c_v2p * ratio * vad;                                 \
    float ht2 = c_vad * vad;                                         \
    float ht3 = c_phr * phr;                                         \
    float aet = fminf(ET_eff * pe, vad);                             \
    vad = vad + infil - aet - ht1 - ht2;                             \
    float overflow = fmaxf(vad - vml, 0.f);                          \
    vad = fminf(fmaxf(vad, NZ), vml);                                \
    ht0 += overflow;                                                 \
    phr = fmaxf(phr + ht1 - ht3, NZ);                                \
    float qdl = ht2 + ht3;                                           \
    _Pragma("unroll")                                                \
    for (int l = 0; l < LENF; ++l) {                                 \
      int s_ = (I_) + l; if (s_ >= LENF) s_ -= LENF;                 \
      acc[s_] = fmaf(w1[l], ht0, acc[s_]);                           \
      acc[s_] = fmaf(w2[l], qdl, acc[s_]);                           \
    }                                                                \
  }

#define COMPUTE_BLOCK(BP, BT, BE)                                    \
  {                                                                  \
    _Pragma("unroll")                                                \
    for (int i = 0; i < LENF; ++i) {                                 \
      STEP(BP[i], BT[i], BE[i], i);                                  \
      *optr = acc[i];                                                \
      acc[i] = 0.f;                                                  \
      optr += G;                                                     \
    }                                                                \
  }

#define COMPUTE_BLOCK_GUARDED(BP, BT, BE, t0)                        \
  {                                                                  \
    _Pragma("unroll")                                                \
    for (int i = 0; i < LENF; ++i) {                                 \
      if ((t0) + i < T) {                                            \
        STEP(BP[i], BT[i], BE[i], i);                                \
        *optr = acc[i];                                              \
        acc[i] = 0.f;                                                \
        optr += G;                                                   \
      }                                                              \
    }                                                                \
  }

  if (nb > 0) LOAD_BLOCK(Ap, At, Ae, 0);

  int k = 0;
  while (k + 2 <= nb) {
    LOAD_BLOCK(Bp, Bt, Be, k + 1);       // prefetch while computing A
    COMPUTE_BLOCK(Ap, At, Ae);
    if (k + 2 < nb) LOAD_BLOCK(Ap, At, Ae, k + 2);
    COMPUTE_BLOCK(Bp, Bt, Be);
    k += 2;
  }
  if (k < nb) {                           // nb odd: last full block from A
    COMPUTE_BLOCK(Ap, At, Ae);
    k += 1;
  }
  if (tail > 0) {                         // generic tail (empty for T=1095)
    LOAD_BLOCK_GUARDED(Ap, At, Ae, nb);
    COMPUTE_BLOCK_GUARDED(Ap, At, Ae, nb * LENF);
  }

#undef LOAD_BLOCK
#undef LOAD_BLOCK_GUARDED
#undef STEP
#undef COMPUTE_BLOCK
#undef COMPUTE_BLOCK_GUARDED
}

extern "C" void kernel_launch(void* const* d_in, const int* in_sizes, int n_in,
                              void* d_out, int out_size, void* d_ws, size_t ws_size,
                              hipStream_t stream) {
  const float* x      = (const float*)d_in[0];
  const float* params = (const float*)d_in[1];
  float* out          = (float*)d_out;

  int G = in_sizes[1] / 16;               // 15000
  int T = in_sizes[0] / (G * 3);          // 1095

  int block = 64;                         // 1 wave/block -> spread waves across CUs
  int grid  = (G + block - 1) / block;
  exphydro_kernel<<<grid, block, 0, stream>>>(x, params, out, G, T);
}

// Round 4
// 149.807 us; speedup vs baseline: 4.0988x; 1.3812x over previous
//
#include <hip/hip_runtime.h>

#define LENF 15
#define NZ   1e-5f

typedef float f32x2 __attribute__((ext_vector_type(2)));

struct R3 { float p, t, e; };   // 12B record, 4B-aligned -> global_load_dwordx3

__global__ __launch_bounds__(64, 1) void exphydro_kernel(
    const float* __restrict__ x,      // (T, G, 3): prcp, tmean, pet
    const float* __restrict__ params, // (G, 16)
    float* __restrict__ out,          // (T, G)
    int G, int T)
{
  int g = blockIdx.x * 64 + threadIdx.x;
  if (g >= G) return;

  // ---- params ----
  const float* pp = params + (size_t)g * 16;
  float P0[16];
#pragma unroll
  for (int i = 0; i < 16; ++i) P0[i] = pp[i];

  const float ddf    = P0[0]  * 40.f;
  const float Tbm    = P0[1]  * 5.f  - 2.f;
  const float wrf    = P0[2]  * 0.5f;
  const float Tbf    = P0[3]  * 7.f  - 5.f;
  const float Kf     = P0[4]  * 5.f;
  const float exp_fe = P0[5];
  const float ET_eff = P0[6];
  const float c_run  = P0[7];
  const float c_v2p  = P0[8]  * (0.02f - 1e-5f) + 1e-5f;
  const float c_vad  = P0[9]  * 0.1f;
  const float c_phr  = P0[10] * (0.01f - 1e-5f) + 1e-5f;
  const float vml    = P0[11] * (500.f - 0.001f) + 0.001f;
  const float a1     = P0[12] * (20.f - 0.3f)  + 0.3f;
  const float b1     = P0[13] * (5.f  - 0.01f) + 0.01f;
  const float a2     = P0[14] * (13.f - 0.5f)  + 0.5f;
  const float b2     = P0[15] * (1.5f - 0.15f) + 0.15f;
  const float inv_vml = 1.f / vml;

  // ---- gamma UH weights (lgamma/theta terms cancel under normalization) ----
  f32x2 wv[LENF];
  {
    float lw1[LENF], lw2[LENF];
    float m1 = -1e30f, m2 = -1e30f;
    const float ib1 = 1.f / b1, ib2 = 1.f / b2;
#pragma unroll
    for (int l = 0; l < LENF; ++l) {
      float tt = l + 0.5f;
      float lt = __logf(tt);
      lw1[l] = (a1 - 1.f) * lt - tt * ib1;
      lw2[l] = (a2 - 1.f) * lt - tt * ib2;
      m1 = fmaxf(m1, lw1[l]);
      m2 = fmaxf(m2, lw2[l]);
    }
    float s1 = 0.f, s2 = 0.f;
    float t1[LENF], t2[LENF];
#pragma unroll
    for (int l = 0; l < LENF; ++l) {
      t1[l] = __expf(lw1[l] - m1); s1 += t1[l];
      t2[l] = __expf(lw2[l] - m2); s2 += t2[l];
    }
    const float r1 = 1.f / s1, r2 = 1.f / s2;
#pragma unroll
    for (int l = 0; l < LENF; ++l) { wv[l].x = t1[l] * r1; wv[l].y = t2[l] * r2; }
  }

  // ---- state + packed scatter-conv ring ----
  float sog = NZ, wis = NZ, vad = NZ, phr = NZ;
  f32x2 acc[LENF];
#pragma unroll
  for (int l = 0; l < LENF; ++l) { acc[l].x = 0.f; acc[l].y = 0.f; }

  const unsigned Gu = (unsigned)G;
  const R3* xg = (const R3*)x + g;    // record index = t*G + g, byte off < 2^31
  float* optr = out + g;

  R3 A[LENF], B[LENF];
  // input-only precompute (prep): pot_freeze, melt_pot, rain, snow, ret_pot
  float pf[LENF], mp[LENF], rn[LENF], sn[LENF], rp[LENF];

  const int nb   = T / LENF;
  const int tail = T - nb * LENF;

#define LOAD(BUF, blk)                                                \
  {                                                                   \
    unsigned b0_ = (unsigned)(blk) * (unsigned)(LENF) * Gu;           \
    _Pragma("unroll")                                                 \
    for (int j = 0; j < LENF; ++j) BUF[j] = xg[b0_ + (unsigned)j * Gu];\
  }

#define LOAD_G(BUF, blk)                                              \
  {                                                                   \
    unsigned b0_ = (unsigned)(blk) * (unsigned)(LENF) * Gu;           \
    _Pragma("unroll")                                                 \
    for (int j = 0; j < LENF; ++j) {                                  \
      if ((blk) * LENF + j < T) BUF[j] = xg[b0_ + (unsigned)j * Gu];  \
      else { BUF[j].p = 0.f; BUF[j].t = 0.f; BUF[j].e = 0.f; }        \
    }                                                                 \
  }

  // state-independent per-input work: all transcendentals live here,
  // 15 independent chains -> issue-bound, fills pipeline.
  // x^e = exp2(e * log2(x)); v_exp_f32/v_log_f32 are base-2 natively.
#define PREP(BUF)                                                     \
  {                                                                   \
    _Pragma("unroll")                                                 \
    for (int j = 0; j < LENF; ++j) {                                  \
      float p_ = BUF[j].p, tm_ = BUF[j].t, pe_ = BUF[j].e;            \
      float r_ = (tm_ >= 0.f) ? p_ : 0.f;                             \
      rn[j] = r_;                                                     \
      sn[j] = p_ - r_;                                                \
      pf[j] = Kf * __builtin_amdgcn_exp2f(                            \
                  exp_fe * __builtin_amdgcn_logf(fmaxf(Tbf - tm_, NZ))); \
      mp[j] = fmaxf(ddf * (tm_ - Tbm), 0.f);                          \
      rp[j] = ET_eff * pe_;                                           \
    }                                                                 \
  }

  // one recurrence step; I_ compile-time after unroll -> static acc indices
#define STEP(I_)                                                      \
  {                                                                   \
    float freeze = fminf(pf[I_], wis);                                \
    wis -= freeze;                                                    \
    float sos = sog + freeze + sn[I_];                                \
    float melt = fminf(mp[I_], sos);                                  \
    sog = sos - melt;                                                 \
    float retention = wrf * sog;                                      \
    float wtmp = wis + melt + rn[I_];                                 \
    float avail = fmaxf(wtmp - retention, 0.f);                       \
    wis = fminf(wtmp, retention);  /* == avail>0 ? retention : wtmp */\
    float ratio = vad * inv_vml;                                      \
    float ht0 = c_run * ratio * avail;                                \
    float infil = avail - ht0;                                        \
    float ht1 = c_v2p * ratio * vad;                                  \
    float ht2 = c_vad * vad;                                          \
    float ht3 = c_phr * phr;                                          \
    float aet = fminf(rp[I_], vad);                                   \
    vad = vad + infil - aet - ht1 - ht2;                              \
    float overflow = fmaxf(vad - vml, 0.f);                           \
    vad = fminf(fmaxf(vad, NZ), vml);                                 \
    ht0 += overflow;                                                  \
    phr = fmaxf(phr + ht1 - ht3, NZ);                                 \
    f32x2 q_; q_.x = ht0; q_.y = ht2 + ht3;                           \
    _Pragma("unroll")                                                 \
    for (int l = 0; l < LENF; ++l) {                                  \
      int s_ = (I_) + l; if (s_ >= LENF) s_ -= LENF;                  \
      acc[s_] += wv[l] * q_;       /* v_pk_fma_f32 candidate */       \
    }                                                                 \
  }

#define BLOCK()                                                       \
  {                                                                   \
    _Pragma("unroll")                                                 \
    for (int i = 0; i < LENF; ++i) {                                  \
      STEP(i);                                                        \
      f32x2 a_ = acc[i];                                              \
      *optr = a_.x + a_.y;                                            \
      acc[i].x = 0.f; acc[i].y = 0.f;                                 \
      optr += G;                                                      \
    }                                                                 \
  }

#define BLOCK_G(t0)                                                   \
  {                                                                   \
    _Pragma("unroll")                                                 \
    for (int i = 0; i < LENF; ++i) {                                  \
      if ((t0) + i < T) {                                             \
        STEP(i);                                                      \
        f32x2 a_ = acc[i];                                            \
        *optr = a_.x + a_.y;                                          \
        acc[i].x = 0.f; acc[i].y = 0.f;                               \
        optr += G;                                                    \
      }                                                               \
    }                                                                 \
  }

  if (nb > 0) LOAD(A, 0);

  int k = 0;
  while (k + 2 <= nb) {
    LOAD(B, k + 1);              // next block's loads fly during prep+compute
    PREP(A);
    BLOCK();
    if (k + 2 < nb) LOAD(A, k + 2);
    PREP(B);
    BLOCK();
    k += 2;
  }
  if (k < nb) {                  // nb odd: final full block already in A
    PREP(A);
    BLOCK();
  }
  if (tail > 0) {                // generic tail (empty at T=1095)
    LOAD_G(A, nb);
    PREP(A);
    BLOCK_G(nb * LENF);
  }

#undef LOAD
#undef LOAD_G
#undef PREP
#undef STEP
#undef BLOCK
#undef BLOCK_G
}

extern "C" void kernel_launch(void* const* d_in, const int* in_sizes, int n_in,
                              void* d_out, int out_size, void* d_ws, size_t ws_size,
                              hipStream_t stream) {
  const float* x      = (const float*)d_in[0];
  const float* params = (const float*)d_in[1];
  float* out          = (float*)d_out;

  int G = in_sizes[1] / 16;               // 15000
  int T = in_sizes[0] / (G * 3);          // 1095

  int block = 64;                         // 1 wave/block, spread across CUs
  int grid  = (G + block - 1) / block;
  exphydro_kernel<<<grid, block, 0, stream>>>(x, params, out, G, T);
}